// Round 7
// baseline (4185.001 us; speedup 1.0000x reference)
//
#include <hip/hip_runtime.h>
#include <math.h>

#define NPFS   4
#define NFM    512
#define NP     256
#define BATCH  128
#define NBLK   (BATCH * NPFS)   // 512 pfaffians
#define THREADS 512

// Register-resident Pfaffian with NAMED float4 registers (L0..L16).
// Round-5/6 lesson: float4 Lb[17] was never promoted by SROA -> scratch
// (VGPR=64, 25 MB scratch writes). Named locals are SSA values; dynamic
// "indexing" is an explicit select chain, so demotion is impossible.
//  - group g = tid>>2 (4 threads) owns rows {g, 255-g} (g==0: row 255 only);
//    rows padded to 4 floats; pair totals <= 65 float4 blocks.
//  - thread h = tid&3 owns blocks pos with pos%4==h -> <= 17 float4.
//  - per step: (A) publish cols k,k+1 -> ck/cp; [BA] (B) argmax; [BB]
//    (C) stage pre-swap row kp -> A2, col kp -> A3; [BC if pivoting]
//    (D) swap in registers + publish tau/v; [BD] (E) rank-2 update
//    (own regs + tv only; next step's BA orders LDS reuse).

#define LREGS(X) X(0) X(1) X(2) X(3) X(4) X(5) X(6) X(7) X(8) \
                 X(9) X(10) X(11) X(12) X(13) X(14) X(15) X(16)

__device__ __forceinline__ float lane_ex(float4 q, int l) {
    float r = q.x;
    r = (l == 1) ? q.y : r;
    r = (l == 2) ? q.z : r;
    r = (l == 3) ? q.w : r;
    return r;
}

extern "C" __global__ __launch_bounds__(THREADS)
__attribute__((amdgpu_waves_per_eu(4, 4)))
void MultiPf_32469952758284_kernel(const float* __restrict__ F,
                                   const int* __restrict__ idx,
                                   float* __restrict__ ws)
{
    __shared__ float ck[NP];        // column k   (fresh each step)
    __shared__ float cp[NP];        // column k+1 (fresh each step)
    __shared__ float tv[2 * NP];    // tv[2c]=tau[c], tv[2c+1]=v[c]
    __shared__ float A2[NP];        // pre-swap row kp: A2[c]=L[kp][c], c in [p,kp)
    __shared__ float A3[NP];        // pre-swap col kp: A3[r]=L[r][kp], r > kp
    __shared__ int   idxL[NP];
    __shared__ float red[8];
    __shared__ float sred[8];
    __shared__ int   redi[8];

    const int tid = threadIdx.x;
    const int bid = blockIdx.x;
    const int b = bid >> 2, s = bid & 3;
    const float* __restrict__ Fs = F + (size_t)s * NFM * NFM;

    const int g  = tid >> 2, h = tid & 3;
    const int R0 = (g == 0) ? 255 : g;
    const int R1 = (g == 0) ? -1  : 255 - g;
    const int nb0 = (R0 + 3) >> 2;
    const int nbT = nb0 + ((g == 0) ? 0 : ((R1 + 3) >> 2));

    if (tid < NP) idxL[tid] = idx[b * NP + tid];
    __syncthreads();

    // ---- named register file for the owned triangle blocks
#define DECLREG(J) float4 L##J = make_float4(0.f, 0.f, 0.f, 0.f);
    LREGS(DECLREG)
#undef DECLREG

    // ---- gather owned blocks into registers
#define GATHER(J) { \
    const int pos = h + 4 * (J); \
    if (pos < nbT) { \
        const bool f = pos < nb0; \
        const int row = f ? R0 : R1; \
        const int cb = (pos - (f ? 0 : nb0)) << 2; \
        const int ir = idxL[row]; \
        float4 val = make_float4(0.f, 0.f, 0.f, 0.f); \
        if (cb + 0 < row) { const int ic = idxL[cb + 0]; \
            val.x = 0.5f * (Fs[(size_t)ir * NFM + ic] - Fs[(size_t)ic * NFM + ir]); } \
        if (cb + 1 < row) { const int ic = idxL[cb + 1]; \
            val.y = 0.5f * (Fs[(size_t)ir * NFM + ic] - Fs[(size_t)ic * NFM + ir]); } \
        if (cb + 2 < row) { const int ic = idxL[cb + 2]; \
            val.z = 0.5f * (Fs[(size_t)ir * NFM + ic] - Fs[(size_t)ic * NFM + ir]); } \
        if (cb + 3 < row) { const int ic = idxL[cb + 3]; \
            val.w = 0.5f * (Fs[(size_t)ir * NFM + ic] - Fs[(size_t)ic * NFM + ir]); } \
        L##J = val; \
    } }
    LREGS(GATHER)
#undef GATHER

    float sgn = 1.0f, la = 0.0f;    // accumulated redundantly on all threads

    for (int k = 0; k < NP; k += 2) {
        const int p = k + 1;
        const int bk = k >> 2, lk = k & 3;   // k even: cols k,k+1 in one block

        // ---- A: publish columns k (rows>k) and k+1 (rows>k+1)
        if (R0 > k && ((bk & 3) == h)) {
            const int slot = (bk - h) >> 2;
            float4 q = make_float4(0.f, 0.f, 0.f, 0.f);
#define PICKA(J) q = ((J) == slot) ? L##J : q;
            LREGS(PICKA)
#undef PICKA
            ck[R0] = lane_ex(q, lk);
            if (R0 > p) cp[R0] = lane_ex(q, lk + 1);
        }
        if (R1 > k) {
            const int pos = nb0 + bk;
            if ((pos & 3) == h) {
                const int slot = (pos - h) >> 2;
                float4 q = make_float4(0.f, 0.f, 0.f, 0.f);
#define PICKB(J) q = ((J) == slot) ? L##J : q;
                LREGS(PICKB)
#undef PICKB
                ck[R1] = lane_ex(q, lk);
                if (R1 > p) cp[R1] = lane_ex(q, lk + 1);
            }
        }
        __syncthreads();   // BA

        // ---- B: argmax_{r>k} |ck[r]|, carrying signed value (= L[kp][k])
        float bval = -1.0f, bsv = 0.0f; int bidx = 0;
        if (tid > k && tid < NP) {
            const float x = ck[tid];
            bval = fabsf(x); bsv = x; bidx = tid;
        }
        for (int o = 32; o > 0; o >>= 1) {
            const float ov = __shfl_down(bval, o);
            const int   oi = __shfl_down(bidx, o);
            const float os = __shfl_down(bsv, o);
            if (ov > bval || (ov == bval && oi < bidx)) { bval = ov; bidx = oi; bsv = os; }
        }
        if ((tid & 63) == 0) {
            const int w = tid >> 6;
            red[w] = bval; redi[w] = bidx; sred[w] = bsv;
        }
        __syncthreads();   // BB

        float cv = red[0], cs = sred[0]; int ci = redi[0];
        #pragma unroll
        for (int w = 1; w < 8; ++w)
            if (red[w] > cv || (red[w] == cv && redi[w] < ci)) { cv = red[w]; ci = redi[w]; cs = sred[w]; }
        const int kp = ci;
        const float piv = -cs;          // A_post[k][k+1] = -L_pre[kp][k]
        const float rpiv = 1.0f / piv;
        if (kp != p) sgn = -sgn;
        if (piv < 0.0f) sgn = -sgn;
        la += logf(fabsf(piv));
        const bool dopiv = (kp != p);   // block-uniform
        const int cq = kp >> 2, kl = kp & 3;

        // ---- C: stage pre-swap row kp (A2) and column kp (A3)
        if (dopiv) {
            if (R0 == kp || R1 == kp) {
                const bool isR0 = (R0 == kp);
                const int rb = isR0 ? 0 : nb0;
#define STAGEROW(J) { \
    const int pos = h + 4 * (J); \
    const bool inrow = isR0 ? (pos < nb0) : (pos >= nb0 && pos < nbT); \
    if (inrow) { \
        const int cb = (pos - rb) << 2; \
        if (cb + 0 >= p && cb + 0 < kp) A2[cb + 0] = L##J.x; \
        if (cb + 1 >= p && cb + 1 < kp) A2[cb + 1] = L##J.y; \
        if (cb + 2 >= p && cb + 2 < kp) A2[cb + 2] = L##J.z; \
        if (cb + 3 >= p && cb + 3 < kp) A2[cb + 3] = L##J.w; \
    } }
                LREGS(STAGEROW)
#undef STAGEROW
            }
            if (R0 > kp && ((cq & 3) == h)) {
                const int slot = (cq - h) >> 2; float v = 0.f;
#define PICKC(J) v = ((J) == slot) ? lane_ex(L##J, kl) : v;
                LREGS(PICKC)
#undef PICKC
                A3[R0] = v;
            }
            if (R1 > kp) {
                const int pos = nb0 + cq;
                if ((pos & 3) == h) {
                    const int slot = (pos - h) >> 2; float v = 0.f;
#define PICKD(J) v = ((J) == slot) ? lane_ex(L##J, kl) : v;
                    LREGS(PICKD)
#undef PICKD
                    A3[R1] = v;
                }
            }
            __syncthreads();   // BC (only when pivoting; uniform condition)
        }

        // ---- D: apply the symmetric swap to registers + publish tau/v.
        // Live targets only: row kp cols (p,kp): L[kp][c] = -L_pre[c][p]
        //                    col kp rows r>kp:   L[r][kp] = L_pre[r][p]
        if (dopiv) {
            if (R0 == kp || R1 == kp) {
                const bool isR0 = (R0 == kp);
                const int rb = isR0 ? 0 : nb0;
#define SWAPROW(J) { \
    const int pos = h + 4 * (J); \
    const bool inrow = isR0 ? (pos < nb0) : (pos >= nb0 && pos < nbT); \
    if (inrow) { \
        const int cb = (pos - rb) << 2; \
        float4 l4 = L##J; \
        l4.x = (cb + 0 > p && cb + 0 < kp) ? -cp[cb + 0] : l4.x; \
        l4.y = (cb + 1 > p && cb + 1 < kp) ? -cp[cb + 1] : l4.y; \
        l4.z = (cb + 2 > p && cb + 2 < kp) ? -cp[cb + 2] : l4.z; \
        l4.w = (cb + 3 > p && cb + 3 < kp) ? -cp[cb + 3] : l4.w; \
        L##J = l4; \
    } }
                LREGS(SWAPROW)
#undef SWAPROW
            }
            if (R0 > kp && ((cq & 3) == h)) {
                const int slot = (cq - h) >> 2;
                const float nv = cp[R0];
#define SETKL0(J) if ((J) == slot) { float4 l4 = L##J; \
    l4.x = (kl == 0) ? nv : l4.x; l4.y = (kl == 1) ? nv : l4.y; \
    l4.z = (kl == 2) ? nv : l4.z; l4.w = (kl == 3) ? nv : l4.w; L##J = l4; }
                LREGS(SETKL0)
#undef SETKL0
            }
            if (R1 > kp) {
                const int pos = nb0 + cq;
                if ((pos & 3) == h) {
                    const int slot = (pos - h) >> 2;
                    const float nv = cp[R1];
#define SETKL1(J) if ((J) == slot) { float4 l4 = L##J; \
    l4.x = (kl == 0) ? nv : l4.x; l4.y = (kl == 1) ? nv : l4.y; \
    l4.z = (kl == 2) ? nv : l4.z; l4.w = (kl == 3) ? nv : l4.w; L##J = l4; }
                    LREGS(SETKL1)
#undef SETKL1
                }
            }
        }
        {
            const int r = tid;
            if (r >= k + 2 && r < NP) {
                const float t = ((dopiv && r == kp) ? ck[p] : ck[r]) * rpiv;
                float v;
                if (!dopiv)       v = cp[r];
                else if (r < kp)  v = -A2[r];
                else if (r == kp) v = -A2[p];
                else              v = A3[r];
                tv[2 * r] = t; tv[2 * r + 1] = v;
            }
            if (r == k || r == p) { tv[2 * r] = 0.0f; tv[2 * r + 1] = 0.0f; }
        }
        __syncthreads();   // BD

        // ---- E: rank-2 register update: L[r][c] += v[r]*tau[c] - tau[r]*v[c]
        {
            const int c2 = k + 2;
            float tR0 = 0.f, vR0 = 0.f, tR1 = 0.f, vR1 = 0.f;
            if (R0 >= c2) { tR0 = tv[2 * R0]; vR0 = tv[2 * R0 + 1]; }
            if (R1 >= c2) { tR1 = tv[2 * R1]; vR1 = tv[2 * R1 + 1]; }
#define UPDATE(J) { \
    const int pos = h + 4 * (J); \
    if (pos < nbT) { \
        const bool f = pos < nb0; \
        const int row = f ? R0 : R1; \
        const int cb = (pos - (f ? 0 : nb0)) << 2; \
        if (row >= c2 && cb + 3 >= c2) { \
            const float tr = f ? tR0 : tR1; \
            const float vr = f ? vR0 : vR1; \
            const float4 q0 = *(const float4*)(tv + 2 * cb); \
            const float4 q1 = *(const float4*)(tv + 2 * cb + 4); \
            float4 l = L##J; \
            l.x += vr * q0.x - tr * q0.y; \
            l.y += vr * q0.z - tr * q0.w; \
            l.z += vr * q1.x - tr * q1.y; \
            l.w += vr * q1.z - tr * q1.w; \
            L##J = l; \
        } \
    } }
            LREGS(UPDATE)
#undef UPDATE
        }
    }

    if (tid == 0) {
        ws[bid * 2 + 0] = sgn;
        ws[bid * 2 + 1] = la;
    }
}

extern "C" __global__ void MultiPf_combine_kernel(const float* __restrict__ ws,
                                                  float* __restrict__ out)
{
    int b = threadIdx.x + blockIdx.x * blockDim.x;
    if (b >= BATCH) return;
    float sg[NPFS], lg[NPFS];
    float m = -INFINITY;
    for (int j = 0; j < NPFS; ++j) {
        sg[j] = ws[(b * NPFS + j) * 2 + 0];
        lg[j] = ws[(b * NPFS + j) * 2 + 1];
        m = fmaxf(m, lg[j]);
    }
    float val = 0.0f;
    for (int j = 0; j < NPFS; ++j)
        val += sg[j] * expf(lg[j] - m);
    float osgn = (val > 0.0f) ? 1.0f : ((val < 0.0f) ? -1.0f : 0.0f);
    out[b]         = osgn;
    out[BATCH + b] = m + logf(fabsf(val));
}

extern "C" void kernel_launch(void* const* d_in, const int* in_sizes, int n_in,
                              void* d_out, int out_size, void* d_ws, size_t ws_size,
                              hipStream_t stream)
{
    (void)in_sizes; (void)n_in; (void)out_size; (void)ws_size;
    const float* F   = (const float*)d_in[0];
    const int*   idx = (const int*)d_in[1];
    float* out = (float*)d_out;
    float* ws  = (float*)d_ws;

    MultiPf_32469952758284_kernel<<<NBLK, THREADS, 0, stream>>>(F, idx, ws);
    MultiPf_combine_kernel<<<1, 128, 0, stream>>>(ws, out);
}

// Round 8
// 3564.699 us; speedup vs baseline: 1.1740x; 1.1740x over previous
//
#include <hip/hip_runtime.h>
#include <math.h>

#define NPFS   4
#define NFM    512
#define NP     256
#define BATCH  128
#define NBLK   (BATCH * NPFS)   // 512 pfaffians
#define THREADS 1024
#define NWAVES (THREADS / 64)   // 16

// Register-resident Pfaffian, 1024 threads/block, 8 threads per row-pair.
// Round-7 lesson: the allocator pins 64 VGPRs/wave regardless of
// launch-bounds/waves-per-eu hints; 17 float4 (68 VGPRs) of data cannot fit
// -> forced spill (5.5 GB scratch traffic). Fix: 8 threads per row-pair so
// each thread owns <= 9 float4 (36 VGPRs); peak live set ~58 VGPRs fits the
// 64 budget BY CONSTRUCTION. Named registers L0..L8 (X-macro) keep SROA out
// of the picture entirely.
//  - group g = tid>>3 owns rows {g, 255-g} (g==0: row 255 only); rows padded
//    to 4 floats; pair totals <= 65 float4 blocks; thread h = tid&7 owns
//    blocks pos with pos%8==h (pos < nbT) -> <= 9 float4.
//  - per step: (A) publish cols k,k+1 -> ck/cp; [BA] (B) argmax; [BB]
//    (C) stage pre-swap row kp -> A2, col kp -> A3; [BC if pivoting]
//    (D) swap in registers + publish tau/v; [BD] (E) rank-2 update
//    (own regs + tv only; next step's BA orders LDS reuse).
//  - at <=64 VGPRs: 2 blocks/CU -> all 512 pfaffians resident, one round.

#define LREGS(X) X(0) X(1) X(2) X(3) X(4) X(5) X(6) X(7) X(8)

__device__ __forceinline__ float lane_ex(float4 q, int l) {
    float r = q.x;
    r = (l == 1) ? q.y : r;
    r = (l == 2) ? q.z : r;
    r = (l == 3) ? q.w : r;
    return r;
}

extern "C" __global__ __launch_bounds__(THREADS)
__attribute__((amdgpu_waves_per_eu(8)))
void MultiPf_32469952758284_kernel(const float* __restrict__ F,
                                   const int* __restrict__ idx,
                                   float* __restrict__ ws)
{
    __shared__ float ck[NP];        // column k   (fresh each step)
    __shared__ float cp[NP];        // column k+1 (fresh each step)
    __shared__ float tv[2 * NP];    // tv[2c]=tau[c], tv[2c+1]=v[c]
    __shared__ float A2[NP];        // pre-swap row kp: A2[c]=L[kp][c], c in [p,kp)
    __shared__ float A3[NP];        // pre-swap col kp: A3[r]=L[r][kp], r > kp
    __shared__ int   idxL[NP];
    __shared__ float red[NWAVES];
    __shared__ float sred[NWAVES];
    __shared__ int   redi[NWAVES];

    const int tid = threadIdx.x;
    const int bid = blockIdx.x;
    const int b = bid >> 2, s = bid & 3;
    const float* __restrict__ Fs = F + (size_t)s * NFM * NFM;

    const int g  = tid >> 3, h = tid & 7;
    const int R0 = (g == 0) ? 255 : g;
    const int R1 = (g == 0) ? -1  : 255 - g;
    const int nb0 = (R0 + 3) >> 2;
    const int nbT = nb0 + ((g == 0) ? 0 : ((R1 + 3) >> 2));

    if (tid < NP) idxL[tid] = idx[b * NP + tid];
    __syncthreads();

    // ---- named register file for the owned triangle blocks
#define DECLREG(J) float4 L##J = make_float4(0.f, 0.f, 0.f, 0.f);
    LREGS(DECLREG)
#undef DECLREG

    // ---- gather owned blocks into registers
#define GATHER(J) { \
    const int pos = h + 8 * (J); \
    if (pos < nbT) { \
        const bool f = pos < nb0; \
        const int row = f ? R0 : R1; \
        const int cb = (pos - (f ? 0 : nb0)) << 2; \
        const int ir = idxL[row]; \
        float4 val = make_float4(0.f, 0.f, 0.f, 0.f); \
        if (cb + 0 < row) { const int ic = idxL[cb + 0]; \
            val.x = 0.5f * (Fs[(size_t)ir * NFM + ic] - Fs[(size_t)ic * NFM + ir]); } \
        if (cb + 1 < row) { const int ic = idxL[cb + 1]; \
            val.y = 0.5f * (Fs[(size_t)ir * NFM + ic] - Fs[(size_t)ic * NFM + ir]); } \
        if (cb + 2 < row) { const int ic = idxL[cb + 2]; \
            val.z = 0.5f * (Fs[(size_t)ir * NFM + ic] - Fs[(size_t)ic * NFM + ir]); } \
        if (cb + 3 < row) { const int ic = idxL[cb + 3]; \
            val.w = 0.5f * (Fs[(size_t)ir * NFM + ic] - Fs[(size_t)ic * NFM + ir]); } \
        L##J = val; \
    } }
    LREGS(GATHER)
#undef GATHER

    float sgn = 1.0f, la = 0.0f;    // accumulated redundantly on all threads

    for (int k = 0; k < NP; k += 2) {
        const int p = k + 1;
        const int bk = k >> 2, lk = k & 3;   // k even: cols k,k+1 in one block

        // ---- A: publish columns k (rows>k) and k+1 (rows>k+1)
        if (R0 > k && ((bk & 7) == h)) {
            const int slot = bk >> 3;
            float4 q = make_float4(0.f, 0.f, 0.f, 0.f);
#define PICKA(J) q = ((J) == slot) ? L##J : q;
            LREGS(PICKA)
#undef PICKA
            ck[R0] = lane_ex(q, lk);
            if (R0 > p) cp[R0] = lane_ex(q, lk + 1);
        }
        if (R1 > k) {
            const int pos = nb0 + bk;
            if ((pos & 7) == h) {
                const int slot = pos >> 3;
                float4 q = make_float4(0.f, 0.f, 0.f, 0.f);
#define PICKB(J) q = ((J) == slot) ? L##J : q;
                LREGS(PICKB)
#undef PICKB
                ck[R1] = lane_ex(q, lk);
                if (R1 > p) cp[R1] = lane_ex(q, lk + 1);
            }
        }
        __syncthreads();   // BA

        // ---- B: argmax_{r>k} |ck[r]|, carrying signed value (= L[kp][k])
        float bval = -1.0f, bsv = 0.0f; int bidx = 0;
        if (tid > k && tid < NP) {
            const float x = ck[tid];
            bval = fabsf(x); bsv = x; bidx = tid;
        }
        for (int o = 32; o > 0; o >>= 1) {
            const float ov = __shfl_down(bval, o);
            const int   oi = __shfl_down(bidx, o);
            const float os = __shfl_down(bsv, o);
            if (ov > bval || (ov == bval && oi < bidx)) { bval = ov; bidx = oi; bsv = os; }
        }
        if ((tid & 63) == 0) {
            const int w = tid >> 6;
            red[w] = bval; redi[w] = bidx; sred[w] = bsv;
        }
        __syncthreads();   // BB

        float cv = red[0], cs = sred[0]; int ci = redi[0];
        #pragma unroll
        for (int w = 1; w < NWAVES; ++w)
            if (red[w] > cv || (red[w] == cv && redi[w] < ci)) { cv = red[w]; ci = redi[w]; cs = sred[w]; }
        const int kp = ci;
        const float piv = -cs;          // A_post[k][k+1] = -L_pre[kp][k]
        const float rpiv = 1.0f / piv;
        if (kp != p) sgn = -sgn;
        if (piv < 0.0f) sgn = -sgn;
        la += logf(fabsf(piv));
        const bool dopiv = (kp != p);   // block-uniform
        const int cq = kp >> 2, kl = kp & 3;

        // ---- C: stage pre-swap row kp (A2) and column kp (A3)
        if (dopiv) {
            if (R0 == kp || R1 == kp) {
                const bool isR0 = (R0 == kp);
                const int rb = isR0 ? 0 : nb0;
#define STAGEROW(J) { \
    const int pos = h + 8 * (J); \
    const bool inrow = isR0 ? (pos < nb0) : (pos >= nb0 && pos < nbT); \
    if (inrow) { \
        const int cb = (pos - rb) << 2; \
        if (cb + 0 >= p && cb + 0 < kp) A2[cb + 0] = L##J.x; \
        if (cb + 1 >= p && cb + 1 < kp) A2[cb + 1] = L##J.y; \
        if (cb + 2 >= p && cb + 2 < kp) A2[cb + 2] = L##J.z; \
        if (cb + 3 >= p && cb + 3 < kp) A2[cb + 3] = L##J.w; \
    } }
                LREGS(STAGEROW)
#undef STAGEROW
            }
            if (R0 > kp && ((cq & 7) == h)) {
                const int slot = cq >> 3; float v = 0.f;
#define PICKC(J) v = ((J) == slot) ? lane_ex(L##J, kl) : v;
                LREGS(PICKC)
#undef PICKC
                A3[R0] = v;
            }
            if (R1 > kp) {
                const int pos = nb0 + cq;
                if ((pos & 7) == h) {
                    const int slot = pos >> 3; float v = 0.f;
#define PICKD(J) v = ((J) == slot) ? lane_ex(L##J, kl) : v;
                    LREGS(PICKD)
#undef PICKD
                    A3[R1] = v;
                }
            }
            __syncthreads();   // BC (only when pivoting; uniform condition)
        }

        // ---- D: apply the symmetric swap to registers + publish tau/v.
        // Live targets only: row kp cols (p,kp): L[kp][c] = -L_pre[c][p]
        //                    col kp rows r>kp:   L[r][kp] = L_pre[r][p]
        if (dopiv) {
            if (R0 == kp || R1 == kp) {
                const bool isR0 = (R0 == kp);
                const int rb = isR0 ? 0 : nb0;
#define SWAPROW(J) { \
    const int pos = h + 8 * (J); \
    const bool inrow = isR0 ? (pos < nb0) : (pos >= nb0 && pos < nbT); \
    if (inrow) { \
        const int cb = (pos - rb) << 2; \
        float4 l4 = L##J; \
        l4.x = (cb + 0 > p && cb + 0 < kp) ? -cp[cb + 0] : l4.x; \
        l4.y = (cb + 1 > p && cb + 1 < kp) ? -cp[cb + 1] : l4.y; \
        l4.z = (cb + 2 > p && cb + 2 < kp) ? -cp[cb + 2] : l4.z; \
        l4.w = (cb + 3 > p && cb + 3 < kp) ? -cp[cb + 3] : l4.w; \
        L##J = l4; \
    } }
                LREGS(SWAPROW)
#undef SWAPROW
            }
            if (R0 > kp && ((cq & 7) == h)) {
                const int slot = cq >> 3;
                const float nv = cp[R0];
#define SETKL0(J) if ((J) == slot) { float4 l4 = L##J; \
    l4.x = (kl == 0) ? nv : l4.x; l4.y = (kl == 1) ? nv : l4.y; \
    l4.z = (kl == 2) ? nv : l4.z; l4.w = (kl == 3) ? nv : l4.w; L##J = l4; }
                LREGS(SETKL0)
#undef SETKL0
            }
            if (R1 > kp) {
                const int pos = nb0 + cq;
                if ((pos & 7) == h) {
                    const int slot = pos >> 3;
                    const float nv = cp[R1];
#define SETKL1(J) if ((J) == slot) { float4 l4 = L##J; \
    l4.x = (kl == 0) ? nv : l4.x; l4.y = (kl == 1) ? nv : l4.y; \
    l4.z = (kl == 2) ? nv : l4.z; l4.w = (kl == 3) ? nv : l4.w; L##J = l4; }
                    LREGS(SETKL1)
#undef SETKL1
                }
            }
        }
        {
            const int r = tid;
            if (r >= k + 2 && r < NP) {
                const float t = ((dopiv && r == kp) ? ck[p] : ck[r]) * rpiv;
                float v;
                if (!dopiv)       v = cp[r];
                else if (r < kp)  v = -A2[r];
                else if (r == kp) v = -A2[p];
                else              v = A3[r];
                tv[2 * r] = t; tv[2 * r + 1] = v;
            }
            if (r == k || r == p) { tv[2 * r] = 0.0f; tv[2 * r + 1] = 0.0f; }
        }
        __syncthreads();   // BD

        // ---- E: rank-2 register update: L[r][c] += v[r]*tau[c] - tau[r]*v[c]
        {
            const int c2 = k + 2;
            const float tR0 = tv[2 * R0], vR0 = tv[2 * R0 + 1];   // stale-safe:
            const float tR1 = tv[2 * ((R1 < 0) ? 0 : R1)];        // guarded by
            const float vR1 = tv[2 * ((R1 < 0) ? 0 : R1) + 1];    // row>=c2 below
#define UPDATE(J) { \
    const int pos = h + 8 * (J); \
    if (pos < nbT) { \
        const bool f = pos < nb0; \
        const int row = f ? R0 : R1; \
        const int cb = (pos - (f ? 0 : nb0)) << 2; \
        if (row >= c2 && cb + 3 >= c2) { \
            const float tr = f ? tR0 : tR1; \
            const float vr = f ? vR0 : vR1; \
            const float4 q0 = *(const float4*)(tv + 2 * cb); \
            const float4 q1 = *(const float4*)(tv + 2 * cb + 4); \
            float4 l = L##J; \
            l.x += vr * q0.x - tr * q0.y; \
            l.y += vr * q0.z - tr * q0.w; \
            l.z += vr * q1.x - tr * q1.y; \
            l.w += vr * q1.z - tr * q1.w; \
            L##J = l; \
        } \
    } }
            LREGS(UPDATE)
#undef UPDATE
        }
    }

    if (tid == 0) {
        ws[bid * 2 + 0] = sgn;
        ws[bid * 2 + 1] = la;
    }
}

extern "C" __global__ void MultiPf_combine_kernel(const float* __restrict__ ws,
                                                  float* __restrict__ out)
{
    int b = threadIdx.x + blockIdx.x * blockDim.x;
    if (b >= BATCH) return;
    float sg[NPFS], lg[NPFS];
    float m = -INFINITY;
    for (int j = 0; j < NPFS; ++j) {
        sg[j] = ws[(b * NPFS + j) * 2 + 0];
        lg[j] = ws[(b * NPFS + j) * 2 + 1];
        m = fmaxf(m, lg[j]);
    }
    float val = 0.0f;
    for (int j = 0; j < NPFS; ++j)
        val += sg[j] * expf(lg[j] - m);
    float osgn = (val > 0.0f) ? 1.0f : ((val < 0.0f) ? -1.0f : 0.0f);
    out[b]         = osgn;
    out[BATCH + b] = m + logf(fabsf(val));
}

extern "C" void kernel_launch(void* const* d_in, const int* in_sizes, int n_in,
                              void* d_out, int out_size, void* d_ws, size_t ws_size,
                              hipStream_t stream)
{
    (void)in_sizes; (void)n_in; (void)out_size; (void)ws_size;
    const float* F   = (const float*)d_in[0];
    const int*   idx = (const int*)d_in[1];
    float* out = (float*)d_out;
    float* ws  = (float*)d_ws;

    MultiPf_32469952758284_kernel<<<NBLK, THREADS, 0, stream>>>(F, idx, ws);
    MultiPf_combine_kernel<<<1, 128, 0, stream>>>(ws, out);
}